// Round 4
// baseline (1013.827 us; speedup 1.0000x reference)
//
#include <hip/hip_runtime.h>

#define DI __device__ __forceinline__

#define B_ 8
#define N_ 4096
#define S_ 1024
#define K_ 32
#define M_TOT (B_ * S_ * K_)   // 262144 rows
#define NBLK 2048              // M_TOT / 128

typedef float f32x2 __attribute__((ext_vector_type(2)));

// Exact-IEEE squared distance, matching numpy f32 eval order ((dx*dx+dy*dy)+dz*dz),
// _rn intrinsics block FMA contraction so indices match the reference bit-exactly.
DI float sqdist_rn(float ax, float ay, float az, float bx, float by, float bz) {
    float dx = __fsub_rn(ax, bx);
    float dy = __fsub_rn(ay, by);
    float dz = __fsub_rn(az, bz);
    return __fadd_rn(__fadd_rn(__fmul_rn(dx, dx), __fmul_rn(dy, dy)), __fmul_rn(dz, dz));
}

DI unsigned short f2b(float f) {  // f32 -> bf16 RNE
    unsigned u = __float_as_uint(f);
    return (unsigned short)((u + 0x7FFFu + ((u >> 16) & 1u)) >> 16);
}
DI float b2f(unsigned short h) { return __uint_as_float(((unsigned)h) << 16); }

// VOP3P packed f32 ops: two independent IEEE-RN f32 ops per instruction.
DI f32x2 pk_add(f32x2 a, f32x2 b) {
    f32x2 r;
    asm("v_pk_add_f32 %0, %1, %2" : "=v"(r) : "v"(a), "v"(b));
    return r;
}
DI f32x2 pk_mul(f32x2 a, f32x2 b) {
    f32x2 r;
    asm("v_pk_mul_f32 %0, %1, %2" : "=v"(r) : "v"(a), "v"(b));
    return r;
}

// DPP permutation applied to a u64 as two 32-bit halves (VALU-speed cross-lane).
template <int CTRL>
DI unsigned long long dpp_u64(unsigned long long v) {
    unsigned lo = (unsigned)__builtin_amdgcn_update_dpp(
        0, (int)(unsigned)v, CTRL, 0xF, 0xF, true);
    unsigned hi = (unsigned)__builtin_amdgcn_update_dpp(
        0, (int)(unsigned)(v >> 32), CTRL, 0xF, 0xF, true);
    return ((unsigned long long)hi << 32) | lo;
}
DI unsigned long long umax64(unsigned long long a, unsigned long long b) {
    return a > b ? a : b;
}

// ---------------- FPS: one block per batch, 1 barrier/step, DPP wave reduce ----------------
// Per step: packed-pair dists (v_pk_*, exact IEEE order, subtract via sign-xor'd
// centroid) -> u64 packed-key tree -> 6-stage DPP reduce to lane 63 -> wave partial ->
// barrier -> all threads redundantly reduce 8 partials -> broadcast LDS read of winner
// coords. Winner indices logged to LDS; new_xyz written once post-loop (keeps global
// stores + their vmcnt barrier-drain out of the sequential loop).
__global__ __launch_bounds__(512) void fps_kernel(const float* __restrict__ xyz,
                                                  float* __restrict__ new_xyz) {
    const int b = blockIdx.x;
    const int t = threadIdx.x;
    const float* X = xyz + (size_t)b * (N_ * 3);
    __shared__ float4 pts[N_];                         // 64 KB coord table
    __shared__ unsigned idxs[S_];                      // 4 KB winner log
    __shared__ __align__(16) unsigned long long part[2][8];
    f32x2 px2[4], py2[4], pz2[4], dd2[4];
    unsigned nlo[8];
#pragma unroll
    for (int j = 0; j < 8; ++j) {
        int p = t + 512 * j;
        float x = X[p * 3 + 0], y = X[p * 3 + 1], z = X[p * 3 + 2];
        px2[j >> 1][j & 1] = x;
        py2[j >> 1][j & 1] = y;
        pz2[j >> 1][j & 1] = z;
        dd2[j >> 1][j & 1] = 1e10f;
        nlo[j] = ~(unsigned)p;
        pts[p] = make_float4(x, y, z, 0.0f);
    }
    __syncthreads();
    float4 cent = pts[0];
    if (t == 0) idxs[0] = 0;
    for (int i = 1; i < S_; ++i) {
        // negated centroid pairs (sign-bit xor = exact negation; a + (-c) == a - c)
        f32x2 ncx, ncy, ncz;
        ncx.x = ncx.y = __uint_as_float(__float_as_uint(cent.x) ^ 0x80000000u);
        ncy.x = ncy.y = __uint_as_float(__float_as_uint(cent.y) ^ 0x80000000u);
        ncz.x = ncz.y = __uint_as_float(__float_as_uint(cent.z) ^ 0x80000000u);
        unsigned long long k0[8];
#pragma unroll
        for (int q = 0; q < 4; ++q) {
            f32x2 dx = pk_add(px2[q], ncx);
            f32x2 dy = pk_add(py2[q], ncy);
            f32x2 dz = pk_add(pz2[q], ncz);
            f32x2 d  = pk_add(pk_add(pk_mul(dx, dx), pk_mul(dy, dy)), pk_mul(dz, dz));
            dd2[q].x = fminf(dd2[q].x, d.x);
            dd2[q].y = fminf(dd2[q].y, d.y);
            // u64 key: max dist wins, tie -> lower point index (np.argmax first-max)
            k0[2 * q + 0] = ((unsigned long long)__float_as_uint(dd2[q].x) << 32) |
                            (unsigned long long)nlo[2 * q + 0];
            k0[2 * q + 1] = ((unsigned long long)__float_as_uint(dd2[q].y) << 32) |
                            (unsigned long long)nlo[2 * q + 1];
        }
        k0[0] = umax64(k0[0], k0[1]);
        k0[2] = umax64(k0[2], k0[3]);
        k0[4] = umax64(k0[4], k0[5]);
        k0[6] = umax64(k0[6], k0[7]);
        k0[0] = umax64(k0[0], k0[2]);
        k0[4] = umax64(k0[4], k0[6]);
        unsigned long long key = umax64(k0[0], k0[4]);
        // wave reduce to lane 63, VALU DPP (no LDS pipe)
        key = umax64(key, dpp_u64<0x111>(key));  // row_shr:1
        key = umax64(key, dpp_u64<0x112>(key));  // row_shr:2
        key = umax64(key, dpp_u64<0x114>(key));  // row_shr:4
        key = umax64(key, dpp_u64<0x118>(key));  // row_shr:8
        key = umax64(key, dpp_u64<0x142>(key));  // row_bcast15
        key = umax64(key, dpp_u64<0x143>(key));  // row_bcast31
        if ((t & 63) == 63) part[i & 1][t >> 6] = key;
        __syncthreads();
        // redundant final reduce in every thread -> no second barrier needed
        ulonglong2 q0 = *(const ulonglong2*)&part[i & 1][0];
        ulonglong2 q1 = *(const ulonglong2*)&part[i & 1][2];
        ulonglong2 q2 = *(const ulonglong2*)&part[i & 1][4];
        ulonglong2 q3 = *(const ulonglong2*)&part[i & 1][6];
        unsigned long long ka = umax64(umax64(q0.x, q0.y), umax64(q1.x, q1.y));
        unsigned long long kb = umax64(umax64(q2.x, q2.y), umax64(q3.x, q3.y));
        unsigned long long k = umax64(ka, kb);
        unsigned gidx = ~(unsigned)(k & 0xFFFFFFFFull);
        cent = pts[gidx];            // uniform address -> LDS broadcast
        idxs[i] = gidx;              // all lanes, same addr+value: 1 inst, no branch
    }
    __syncthreads();
    // post-loop writeout (global stores kept out of the sequential loop)
    for (int c = t; c < S_; c += 512) {
        float4 p = pts[idxs[c]];
        size_t o3 = ((size_t)b * S_ + c) * 3;
        new_xyz[o3 + 0] = p.x;
        new_xyz[o3 + 1] = p.y;
        new_xyz[o3 + 2] = p.z;
    }
}

// ---------------- Ball query: one wave per center, ordered compaction ----------------
__global__ __launch_bounds__(256) void qb_kernel(const float* __restrict__ xyz,
                                                 const float* __restrict__ new_xyz,
                                                 int* __restrict__ idxbuf) {
    const int c = blockIdx.x * 4 + (threadIdx.x >> 6);
    const int lane = threadIdx.x & 63;
    const int b = c >> 10;
    const float* X = xyz + (size_t)b * (N_ * 3);
    const float cx = new_xyz[c * 3 + 0];
    const float cy = new_xyz[c * 3 + 1];
    const float cz = new_xyz[c * 3 + 2];
    int* out = idxbuf + (size_t)c * K_;
    int taken = 0, first = -1;
    for (int ch = 0; ch < 64; ++ch) {
        int p = ch * 64 + lane;
        float d = sqdist_rn(X[p * 3 + 0], X[p * 3 + 1], X[p * 3 + 2], cx, cy, cz);
        bool ok = (d <= 0.25f);  // sqr > r^2 excluded => include <=
        unsigned long long m = __ballot(ok);
        if (first < 0 && m) first = ch * 64 + (__ffsll((unsigned long long)m) - 1);
        int pos = taken + (int)__popcll(m & ((1ull << lane) - 1ull));
        if (ok && pos < K_) out[pos] = p;
        taken += (int)__popcll(m);
        if (taken >= K_) break;
    }
    int filled = taken < K_ ? taken : K_;
    if (lane >= filled && lane < K_) out[lane] = first;
}

// ---------------- shared GEMM tile: 128 rows x (16*CC) outs, f32 register tile ----------------
template <int FS, int SLOTS, int CC>
DI void gemm_tile(const float* __restrict__ feat, const float* __restrict__ wl,
                  const float* __restrict__ bias, unsigned short* __restrict__ yout,
                  float* __restrict__ ps, float* __restrict__ pq,
                  int r0, int tid, int blk) {
    const int tr = tid & 15;
    const int tc = tid >> 4;
    float acc[8][CC];
#pragma unroll
    for (int rr = 0; rr < 8; ++rr)
#pragma unroll
        for (int cc = 0; cc < CC; ++cc) acc[rr][cc] = 0.0f;

#pragma unroll 2
    for (int sl = 0; sl < SLOTS; ++sl) {
        float4 xv[8], wv[CC];
#pragma unroll
        for (int rr = 0; rr < 8; ++rr)
            xv[rr] = *(const float4*)&feat[(tr + 16 * rr) * FS + 4 * sl];
#pragma unroll
        for (int cc = 0; cc < CC; ++cc)
            wv[cc] = *(const float4*)&wl[(tc + 16 * cc) * FS + 4 * sl];
#pragma unroll
        for (int rr = 0; rr < 8; ++rr)
#pragma unroll
            for (int cc = 0; cc < CC; ++cc)
                acc[rr][cc] = fmaf(xv[rr].x, wv[cc].x,
                               fmaf(xv[rr].y, wv[cc].y,
                                fmaf(xv[rr].z, wv[cc].z,
                                 fmaf(xv[rr].w, wv[cc].w, acc[rr][cc]))));
    }
    float s1[CC], s2[CC];
#pragma unroll
    for (int cc = 0; cc < CC; ++cc) {
        const int och = tc + 16 * cc;
        const float bv = bias[och];
        s1[cc] = 0.0f; s2[cc] = 0.0f;
#pragma unroll
        for (int rr = 0; rr < 8; ++rr) {
            float y = acc[rr][cc] + bv;
            const int gr = r0 + tr + 16 * rr;
            yout[(size_t)gr * (16 * CC) + och] = f2b(y);
            s1[cc] += y;
            s2[cc] = fmaf(y, y, s2[cc]);
        }
    }
    // lanes sharing tc butterfly over tr -> complete per-channel block totals, no atomics
#pragma unroll
    for (int m = 1; m < 16; m <<= 1) {
#pragma unroll
        for (int cc = 0; cc < CC; ++cc) {
            s1[cc] += __shfl_xor(s1[cc], m);
            s2[cc] += __shfl_xor(s2[cc], m);
        }
    }
    if ((tid & 15) == 0) {
#pragma unroll
        for (int cc = 0; cc < CC; ++cc) {
            const int och = tc + 16 * cc;
            ps[och * NBLK + blk] = s1[cc];
            pq[och * NBLK + blk] = s2[cc];
        }
    }
}

// ---------------- Layer 1: gather(xyz, xyz-center, points) + GEMM 70->64 ----------------
__global__ __launch_bounds__(256) void layer1_kernel(
    const float* __restrict__ xyz, const float* __restrict__ points,
    const float* __restrict__ new_xyz, const int* __restrict__ idxbuf,
    const float* __restrict__ W, const float* __restrict__ bias,
    unsigned short* __restrict__ yout, float* __restrict__ ps, float* __restrict__ pq) {
    const int tid = threadIdx.x;
    const int blk = blockIdx.x;
    const int r0 = blk * 128;
    __shared__ float feat[128 * 76];   // channels: 0..5 xyz/norm, 6..7 zero pad, 8..71 points
    __shared__ float wl[64 * 76];
    for (int jj = tid; jj < 64 * 70; jj += 256) {
        int o = jj / 70;
        int i = jj - o * 70;
        int mch = (i < 6) ? i : (i + 2);
        wl[o * 76 + mch] = W[jj];
    }
    if (tid < 128) wl[(tid >> 1) * 76 + 6 + (tid & 1)] = 0.0f;
    {
        const int row = tid >> 1, h = tid & 1;
        const int gr = r0 + row;
        const int b = gr >> 15;
        const int s = (gr >> 5) & 1023;
        const int pi = idxbuf[gr];
        const float* P = points + ((size_t)b * N_ + pi) * 64 + h * 32;
        float* fr = &feat[row * 76];
#pragma unroll
        for (int q = 0; q < 8; ++q) {
            float4 v = *(const float4*)(P + 4 * q);
            *(float4*)(fr + 8 + h * 32 + 4 * q) = v;
        }
        if (h == 0) {
            size_t pb = ((size_t)b * N_ + pi) * 3;
            float x = xyz[pb + 0], y = xyz[pb + 1], z = xyz[pb + 2];
            const float* C = new_xyz + ((size_t)b * S_ + s) * 3;
            fr[0] = x; fr[1] = y; fr[2] = z;
            fr[3] = x - C[0]; fr[4] = y - C[1]; fr[5] = z - C[2];
            fr[6] = 0.0f; fr[7] = 0.0f;
        }
    }
    __syncthreads();
    gemm_tile<76, 18, 4>(feat, wl, bias, yout, ps, pq, r0, tid, blk);
}

// ---------------- Layers 2/3: BN(prev)+ReLU on load, GEMM 64->OC ----------------
template <int OC>
__global__ __launch_bounds__(256) void layer23_kernel(
    const unsigned short* __restrict__ yin,
    const float* __restrict__ scale, const float* __restrict__ shift,
    const float* __restrict__ W, const float* __restrict__ bias,
    unsigned short* __restrict__ yout, float* __restrict__ ps, float* __restrict__ pq) {
    const int tid = threadIdx.x;
    const int blk = blockIdx.x;
    const int r0 = blk * 128;
    __shared__ float feat[128 * 68];
    __shared__ float wl[OC * 68];
    __shared__ float ssc[64], ssh[64];
    if (tid < 64) { ssc[tid] = scale[tid]; ssh[tid] = shift[tid]; }
    for (int jj = tid; jj < OC * 64; jj += 256) {
        int o = jj >> 6, i = jj & 63;
        wl[o * 68 + i] = W[jj];
    }
    __syncthreads();
    {
        const int row = tid >> 1, h = tid & 1;
        const int gr = r0 + row;
        const uint4* src = (const uint4*)(yin + (size_t)gr * 64 + h * 32);
        float* fr = &feat[row * 68 + h * 32];
#pragma unroll
        for (int q = 0; q < 4; ++q) {
            uint4 u = src[q];
            const int cb = h * 32 + q * 8;
            float f0 = fmaxf(fmaf(__uint_as_float(u.x << 16),         ssc[cb + 0], ssh[cb + 0]), 0.f);
            float f1 = fmaxf(fmaf(__uint_as_float(u.x & 0xFFFF0000u), ssc[cb + 1], ssh[cb + 1]), 0.f);
            float f2 = fmaxf(fmaf(__uint_as_float(u.y << 16),         ssc[cb + 2], ssh[cb + 2]), 0.f);
            float f3 = fmaxf(fmaf(__uint_as_float(u.y & 0xFFFF0000u), ssc[cb + 3], ssh[cb + 3]), 0.f);
            float f4 = fmaxf(fmaf(__uint_as_float(u.z << 16),         ssc[cb + 4], ssh[cb + 4]), 0.f);
            float f5 = fmaxf(fmaf(__uint_as_float(u.z & 0xFFFF0000u), ssc[cb + 5], ssh[cb + 5]), 0.f);
            float f6 = fmaxf(fmaf(__uint_as_float(u.w << 16),         ssc[cb + 6], ssh[cb + 6]), 0.f);
            float f7 = fmaxf(fmaf(__uint_as_float(u.w & 0xFFFF0000u), ssc[cb + 7], ssh[cb + 7]), 0.f);
            *(float4*)(fr + 8 * q)     = make_float4(f0, f1, f2, f3);
            *(float4*)(fr + 8 * q + 4) = make_float4(f4, f5, f6, f7);
        }
    }
    __syncthreads();
    gemm_tile<68, 16, OC / 16>(feat, wl, bias, yout, ps, pq, r0, tid, blk);
}

// ---------------- BN stats reduce -> scale/shift ----------------
__global__ __launch_bounds__(256) void bn_reduce_kernel(
    const float* __restrict__ ps, const float* __restrict__ pq,
    const float* __restrict__ gamma, const float* __restrict__ beta,
    float* __restrict__ scale, float* __restrict__ shift) {
    const int o = blockIdx.x, t = threadIdx.x;
    float s1 = 0.f, s2 = 0.f;
    for (int i = t; i < NBLK; i += 256) {
        s1 += ps[o * NBLK + i];
        s2 += pq[o * NBLK + i];
    }
#pragma unroll
    for (int m = 32; m >= 1; m >>= 1) { s1 += __shfl_xor(s1, m); s2 += __shfl_xor(s2, m); }
    __shared__ float a1[4], a2[4];
    if ((t & 63) == 0) { a1[t >> 6] = s1; a2[t >> 6] = s2; }
    __syncthreads();
    if (t == 0) {
        float S1 = a1[0] + a1[1] + a1[2] + a1[3];
        float S2 = a2[0] + a2[1] + a2[2] + a2[3];
        const float inv = 1.0f / (float)M_TOT;
        float mean = S1 * inv;
        float var = S2 * inv - mean * mean;
        if (var < 0.f) var = 0.f;
        float rstd = 1.0f / sqrtf(var + 1e-5f);
        float sc = rstd * gamma[o];
        scale[o] = sc;
        shift[o] = beta[o] - mean * sc;
    }
}

// ---------------- BN3 + ReLU + max over K ----------------
__global__ __launch_bounds__(256) void pool_kernel(
    const unsigned short* __restrict__ y3,
    const float* __restrict__ scale, const float* __restrict__ shift,
    float* __restrict__ outp) {
    const int grp = blockIdx.x * 2 + (threadIdx.x >> 7);
    const int ch = threadIdx.x & 127;
    const unsigned short* Y = y3 + (size_t)grp * (K_ * 128) + ch;
    const float sc = scale[ch], sh = shift[ch];
    float m = -1e30f;
#pragma unroll 8
    for (int k = 0; k < K_; ++k) {
        float v = b2f(Y[k * 128]);
        m = fmaxf(m, fmaf(v, sc, sh));
    }
    outp[(size_t)grp * 128 + ch] = fmaxf(m, 0.0f);  // relu commutes with max
}

extern "C" void kernel_launch(void* const* d_in, const int* in_sizes, int n_in,
                              void* d_out, int out_size, void* d_ws, size_t ws_size,
                              hipStream_t stream) {
    const float* xyz    = (const float*)d_in[0];
    const float* points = (const float*)d_in[1];
    const float* w0  = (const float*)d_in[2];
    const float* b0  = (const float*)d_in[3];
    const float* g0  = (const float*)d_in[4];
    const float* be0 = (const float*)d_in[5];
    const float* w1  = (const float*)d_in[6];
    const float* b1  = (const float*)d_in[7];
    const float* g1  = (const float*)d_in[8];
    const float* be1 = (const float*)d_in[9];
    const float* w2  = (const float*)d_in[10];
    const float* b2  = (const float*)d_in[11];
    const float* g2  = (const float*)d_in[12];
    const float* be2 = (const float*)d_in[13];

    float* out = (float*)d_out;           // [0,24576) new_xyz, [24576,...) new_points
    char* ws = (char*)d_ws;
    int*   idxbuf = (int*)ws;                              // 1 MB
    float* ps  = (float*)(ws + (1 << 20));                 // 1 MB (128ch x 2048 blk)
    float* pq  = (float*)(ws + (2 << 20));                 // 1 MB
    float* st  = (float*)(ws + (3 << 20));                 // scale/shift x3 layers
    float *sc0 = st,        *sh0 = st + 128;
    float *sc1 = st + 256,  *sh1 = st + 384;
    float *sc2 = st + 512,  *sh2 = st + 640;
    unsigned short* y1 = (unsigned short*)(ws + (4 << 20));   // 32 MB (bf16)
    unsigned short* y3 = y1;                                  // 64 MB, reuses y1 (dead)
    unsigned short* y2 = (unsigned short*)(ws + (68 << 20));  // 32 MB
    // total ws footprint: 100 MB

    fps_kernel<<<8, 512, 0, stream>>>(xyz, out);
    qb_kernel<<<2048, 256, 0, stream>>>(xyz, out, idxbuf);
    layer1_kernel<<<NBLK, 256, 0, stream>>>(xyz, points, out, idxbuf, w0, b0, y1, ps, pq);
    bn_reduce_kernel<<<64, 256, 0, stream>>>(ps, pq, g0, be0, sc0, sh0);
    layer23_kernel<64><<<NBLK, 256, 0, stream>>>(y1, sc0, sh0, w1, b1, y2, ps, pq);
    bn_reduce_kernel<<<64, 256, 0, stream>>>(ps, pq, g1, be1, sc1, sh1);
    layer23_kernel<128><<<NBLK, 256, 0, stream>>>(y2, sc1, sh1, w2, b2, y3, ps, pq);
    bn_reduce_kernel<<<128, 256, 0, stream>>>(ps, pq, g2, be2, sc2, sh2);
    pool_kernel<<<4096, 256, 0, stream>>>(y3, sc2, sh2, out + 24576);
}

// Round 5
// 853.278 us; speedup vs baseline: 1.1882x; 1.1882x over previous
//
#include <hip/hip_runtime.h>

#define DI __device__ __forceinline__

#define B_ 8
#define N_ 4096
#define S_ 1024
#define K_ 32
#define M_TOT (B_ * S_ * K_)   // 262144 rows
#define NBLK 2048              // L1 partial-stat blocks (128 rows each)
#define NW 4096                // L2/L3 per-wave partials (64 rows each)

typedef short bf16x8 __attribute__((ext_vector_type(8)));
typedef float f32x4 __attribute__((ext_vector_type(4)));

// Exact-IEEE squared distance, matching numpy f32 eval order ((dx*dx+dy*dy)+dz*dz),
// _rn intrinsics block FMA contraction so indices match the reference bit-exactly.
DI float sqdist_rn(float ax, float ay, float az, float bx, float by, float bz) {
    float dx = __fsub_rn(ax, bx);
    float dy = __fsub_rn(ay, by);
    float dz = __fsub_rn(az, bz);
    return __fadd_rn(__fadd_rn(__fmul_rn(dx, dx), __fmul_rn(dy, dy)), __fmul_rn(dz, dz));
}

DI unsigned short f2b(float f) {  // f32 -> bf16 RNE
    unsigned u = __float_as_uint(f);
    return (unsigned short)((u + 0x7FFFu + ((u >> 16) & 1u)) >> 16);
}
DI float b2f(unsigned short h) { return __uint_as_float(((unsigned)h) << 16); }

// DPP permutation applied to a u64 as two 32-bit halves (VALU-speed cross-lane).
template <int CTRL>
DI unsigned long long dpp_u64(unsigned long long v) {
    unsigned lo = (unsigned)__builtin_amdgcn_update_dpp(
        0, (int)(unsigned)v, CTRL, 0xF, 0xF, true);
    unsigned hi = (unsigned)__builtin_amdgcn_update_dpp(
        0, (int)(unsigned)(v >> 32), CTRL, 0xF, 0xF, true);
    return ((unsigned long long)hi << 32) | lo;
}
DI unsigned long long umax64(unsigned long long a, unsigned long long b) {
    return a > b ? a : b;
}

// ---------------- FPS (R2 version, 621us known-good): 1 barrier/step, DPP reduce ----------
__global__ __launch_bounds__(512) void fps_kernel(const float* __restrict__ xyz,
                                                  float* __restrict__ new_xyz) {
    const int b = blockIdx.x;
    const int t = threadIdx.x;
    const float* X = xyz + (size_t)b * (N_ * 3);
    __shared__ float4 pts[N_];                         // 64 KB coord table
    __shared__ __align__(16) unsigned long long part[2][8];
    float px[8], py[8], pz[8], dd[8];
#pragma unroll
    for (int j = 0; j < 8; ++j) {
        int p = t + 512 * j;
        float x = X[p * 3 + 0], y = X[p * 3 + 1], z = X[p * 3 + 2];
        px[j] = x; py[j] = y; pz[j] = z; dd[j] = 1e10f;
        pts[p] = make_float4(x, y, z, 0.0f);
    }
    if (t == 0) {  // t==0,j==0 holds point 0 = first centroid
        new_xyz[(size_t)b * (S_ * 3) + 0] = px[0];
        new_xyz[(size_t)b * (S_ * 3) + 1] = py[0];
        new_xyz[(size_t)b * (S_ * 3) + 2] = pz[0];
    }
    __syncthreads();
    float4 cent = pts[0];
    for (int i = 1; i < S_; ++i) {
        // per-lane packed keys; u64 max = max dist, tie -> lower point index (np.argmax)
        unsigned long long k0[8];
#pragma unroll
        for (int j = 0; j < 8; ++j) {
            float d = sqdist_rn(px[j], py[j], pz[j], cent.x, cent.y, cent.z);
            dd[j] = fminf(dd[j], d);
            k0[j] = ((unsigned long long)__float_as_uint(dd[j]) << 32) |
                    (unsigned long long)(~(unsigned)(t + 512 * j));
        }
        k0[0] = umax64(k0[0], k0[1]);
        k0[2] = umax64(k0[2], k0[3]);
        k0[4] = umax64(k0[4], k0[5]);
        k0[6] = umax64(k0[6], k0[7]);
        k0[0] = umax64(k0[0], k0[2]);
        k0[4] = umax64(k0[4], k0[6]);
        unsigned long long key = umax64(k0[0], k0[4]);
        // wave reduce to lane 63, VALU DPP (no LDS pipe)
        key = umax64(key, dpp_u64<0x111>(key));  // row_shr:1
        key = umax64(key, dpp_u64<0x112>(key));  // row_shr:2
        key = umax64(key, dpp_u64<0x114>(key));  // row_shr:4
        key = umax64(key, dpp_u64<0x118>(key));  // row_shr:8
        key = umax64(key, dpp_u64<0x142>(key));  // row_bcast15
        key = umax64(key, dpp_u64<0x143>(key));  // row_bcast31
        if ((t & 63) == 63) part[i & 1][t >> 6] = key;
        __syncthreads();
        // redundant final reduce in every thread -> no second barrier needed
        ulonglong2 q0 = *(const ulonglong2*)&part[i & 1][0];
        ulonglong2 q1 = *(const ulonglong2*)&part[i & 1][2];
        ulonglong2 q2 = *(const ulonglong2*)&part[i & 1][4];
        ulonglong2 q3 = *(const ulonglong2*)&part[i & 1][6];
        unsigned long long ka = umax64(umax64(q0.x, q0.y), umax64(q1.x, q1.y));
        unsigned long long kb = umax64(umax64(q2.x, q2.y), umax64(q3.x, q3.y));
        unsigned long long k = umax64(ka, kb);
        unsigned gidx = ~(unsigned)(k & 0xFFFFFFFFull);
        cent = pts[gidx];  // uniform address -> LDS broadcast
        if (t == 0) {
            size_t o3 = ((size_t)b * S_ + i) * 3;
            new_xyz[o3 + 0] = cent.x;
            new_xyz[o3 + 1] = cent.y;
            new_xyz[o3 + 2] = cent.z;
        }
    }
}

// ---------------- Ball query: one wave per center, ordered compaction ----------------
__global__ __launch_bounds__(256) void qb_kernel(const float* __restrict__ xyz,
                                                 const float* __restrict__ new_xyz,
                                                 int* __restrict__ idxbuf) {
    const int c = blockIdx.x * 4 + (threadIdx.x >> 6);
    const int lane = threadIdx.x & 63;
    const int b = c >> 10;
    const float* X = xyz + (size_t)b * (N_ * 3);
    const float cx = new_xyz[c * 3 + 0];
    const float cy = new_xyz[c * 3 + 1];
    const float cz = new_xyz[c * 3 + 2];
    int* out = idxbuf + (size_t)c * K_;
    int taken = 0, first = -1;
    for (int ch = 0; ch < 64; ++ch) {
        int p = ch * 64 + lane;
        float d = sqdist_rn(X[p * 3 + 0], X[p * 3 + 1], X[p * 3 + 2], cx, cy, cz);
        bool ok = (d <= 0.25f);  // sqr > r^2 excluded => include <=
        unsigned long long m = __ballot(ok);
        if (first < 0 && m) first = ch * 64 + (__ffsll((unsigned long long)m) - 1);
        int pos = taken + (int)__popcll(m & ((1ull << lane) - 1ull));
        if (ok && pos < K_) out[pos] = p;
        taken += (int)__popcll(m);
        if (taken >= K_) break;
    }
    int filled = taken < K_ ? taken : K_;
    if (lane >= filled && lane < K_) out[lane] = first;
}

// ---------------- L1 GEMM tile (f32): 128 rows x 64 outs ----------------
template <int FS, int SLOTS, int CC>
DI void gemm_tile(const float* __restrict__ feat, const float* __restrict__ wl,
                  const float* __restrict__ bias, unsigned short* __restrict__ yout,
                  float* __restrict__ ps, float* __restrict__ pq,
                  int r0, int tid, int blk) {
    const int tr = tid & 15;
    const int tc = tid >> 4;
    float acc[8][CC];
#pragma unroll
    for (int rr = 0; rr < 8; ++rr)
#pragma unroll
        for (int cc = 0; cc < CC; ++cc) acc[rr][cc] = 0.0f;

#pragma unroll 2
    for (int sl = 0; sl < SLOTS; ++sl) {
        float4 xv[8], wv[CC];
#pragma unroll
        for (int rr = 0; rr < 8; ++rr)
            xv[rr] = *(const float4*)&feat[(tr + 16 * rr) * FS + 4 * sl];
#pragma unroll
        for (int cc = 0; cc < CC; ++cc)
            wv[cc] = *(const float4*)&wl[(tc + 16 * cc) * FS + 4 * sl];
#pragma unroll
        for (int rr = 0; rr < 8; ++rr)
#pragma unroll
            for (int cc = 0; cc < CC; ++cc)
                acc[rr][cc] = fmaf(xv[rr].x, wv[cc].x,
                               fmaf(xv[rr].y, wv[cc].y,
                                fmaf(xv[rr].z, wv[cc].z,
                                 fmaf(xv[rr].w, wv[cc].w, acc[rr][cc]))));
    }
    float s1[CC], s2[CC];
#pragma unroll
    for (int cc = 0; cc < CC; ++cc) {
        const int och = tc + 16 * cc;
        const float bv = bias[och];
        s1[cc] = 0.0f; s2[cc] = 0.0f;
#pragma unroll
        for (int rr = 0; rr < 8; ++rr) {
            float y = acc[rr][cc] + bv;
            const int gr = r0 + tr + 16 * rr;
            yout[(size_t)gr * (16 * CC) + och] = f2b(y);
            s1[cc] += y;
            s2[cc] = fmaf(y, y, s2[cc]);
        }
    }
#pragma unroll
    for (int m = 1; m < 16; m <<= 1) {
#pragma unroll
        for (int cc = 0; cc < CC; ++cc) {
            s1[cc] += __shfl_xor(s1[cc], m);
            s2[cc] += __shfl_xor(s2[cc], m);
        }
    }
    if ((tid & 15) == 0) {
#pragma unroll
        for (int cc = 0; cc < CC; ++cc) {
            const int och = tc + 16 * cc;
            ps[och * NBLK + blk] = s1[cc];
            pq[och * NBLK + blk] = s2[cc];
        }
    }
}

// ---------------- Layer 1: gather(xyz, xyz-center, points) + f32 GEMM 70->64 -------------
__global__ __launch_bounds__(256) void layer1_kernel(
    const float* __restrict__ xyz, const float* __restrict__ points,
    const float* __restrict__ new_xyz, const int* __restrict__ idxbuf,
    const float* __restrict__ W, const float* __restrict__ bias,
    unsigned short* __restrict__ yout, float* __restrict__ ps, float* __restrict__ pq) {
    const int tid = threadIdx.x;
    const int blk = blockIdx.x;
    const int r0 = blk * 128;
    __shared__ float feat[128 * 76];   // channels: 0..5 xyz/norm, 6..7 zero pad, 8..71 points
    __shared__ float wl[64 * 76];
    for (int jj = tid; jj < 64 * 70; jj += 256) {
        int o = jj / 70;
        int i = jj - o * 70;
        int mch = (i < 6) ? i : (i + 2);
        wl[o * 76 + mch] = W[jj];
    }
    if (tid < 128) wl[(tid >> 1) * 76 + 6 + (tid & 1)] = 0.0f;
    {
        const int row = tid >> 1, h = tid & 1;
        const int gr = r0 + row;
        const int b = gr >> 15;
        const int s = (gr >> 5) & 1023;
        const int pi = idxbuf[gr];
        const float* P = points + ((size_t)b * N_ + pi) * 64 + h * 32;
        float* fr = &feat[row * 76];
#pragma unroll
        for (int q = 0; q < 8; ++q) {
            float4 v = *(const float4*)(P + 4 * q);
            *(float4*)(fr + 8 + h * 32 + 4 * q) = v;
        }
        if (h == 0) {
            size_t pb = ((size_t)b * N_ + pi) * 3;
            float x = xyz[pb + 0], y = xyz[pb + 1], z = xyz[pb + 2];
            const float* C = new_xyz + ((size_t)b * S_ + s) * 3;
            fr[0] = x; fr[1] = y; fr[2] = z;
            fr[3] = x - C[0]; fr[4] = y - C[1]; fr[5] = z - C[2];
            fr[6] = 0.0f; fr[7] = 0.0f;
        }
    }
    __syncthreads();
    gemm_tile<76, 18, 4>(feat, wl, bias, yout, ps, pq, r0, tid, blk);
}

// ---------------- Layers 2/3 (MFMA bf16): BN(prev)+ReLU staging, 256-row blocks ----------
// A = activations [m][k] bf16, B^T = weights w[o][i] bf16 (natural layout), both LDS with
// XOR swizzle byte^=(row&7)<<4 (T2; row-stride-128B b128 reads otherwise 16-way conflict).
// mfma_f32_16x16x32_bf16, verified triple (m89/m92): a-lane: A[l&15][(l>>4)*8+e],
// b-lane: BT[l&15][(l>>4)*8+e], C/D: col=l&15, row=(l>>4)*4+reg.
// LAST: fuse maxpool -> per-(32-row group, och) max/min of pre-BN y (BN linear).
template <int OC, bool LAST>
__global__ __launch_bounds__(256) void layerM_kernel(
    const unsigned short* __restrict__ yin,
    const float* __restrict__ scale, const float* __restrict__ shift,
    const float* __restrict__ W, const float* __restrict__ bias,
    unsigned short* __restrict__ yout,
    float* __restrict__ ps, float* __restrict__ pq,
    float* __restrict__ maxb, float* __restrict__ minb) {
    const int tid = threadIdx.x;
    const int blk = blockIdx.x;
    const int r0 = blk * 256;
    __shared__ unsigned short featA[256 * 64];   // 32 KB, swizzled
    __shared__ unsigned short wlT[OC * 64];      // swizzled
    __shared__ float ssc[64], ssh[64];
    if (tid < 64) { ssc[tid] = scale[tid]; ssh[tid] = shift[tid]; }
    // stage weights f32 -> bf16 (BT layout = natural w[o][i])
#pragma unroll
    for (int it = 0; it < OC / 16; ++it) {
        int q = it * 256 + tid;          // float4 index; 16 quads per 64-wide row
        int och = q >> 4;
        int qq = q & 15;
        float4 wv = *(const float4*)&W[q * 4];
        uint2 pk;
        pk.x = (unsigned)f2b(wv.x) | ((unsigned)f2b(wv.y) << 16);
        pk.y = (unsigned)f2b(wv.z) | ((unsigned)f2b(wv.w) << 16);
        int idx = och * 64 + (((qq * 8) ^ ((och & 7) << 4)) >> 1);
        *(uint2*)&wlT[idx] = pk;
    }
    __syncthreads();   // ssc/ssh ready
    // stage activations: BN(prev)+ReLU in f32, repack bf16, swizzled LDS write
#pragma unroll
    for (int it = 0; it < 8; ++it) {
        int f = it * 256 + tid;          // 16B granule index (2048 total)
        int row = f >> 3, g = f & 7;
        uint4 u = *(const uint4*)&yin[(size_t)(r0 + row) * 64 + g * 8];
        int c = g * 8;
        float f0 = fmaxf(fmaf(__uint_as_float(u.x << 16),         ssc[c + 0], ssh[c + 0]), 0.f);
        float f1 = fmaxf(fmaf(__uint_as_float(u.x & 0xFFFF0000u), ssc[c + 1], ssh[c + 1]), 0.f);
        float f2 = fmaxf(fmaf(__uint_as_float(u.y << 16),         ssc[c + 2], ssh[c + 2]), 0.f);
        float f3 = fmaxf(fmaf(__uint_as_float(u.y & 0xFFFF0000u), ssc[c + 3], ssh[c + 3]), 0.f);
        float f4 = fmaxf(fmaf(__uint_as_float(u.z << 16),         ssc[c + 4], ssh[c + 4]), 0.f);
        float f5 = fmaxf(fmaf(__uint_as_float(u.z & 0xFFFF0000u), ssc[c + 5], ssh[c + 5]), 0.f);
        float f6 = fmaxf(fmaf(__uint_as_float(u.w << 16),         ssc[c + 6], ssh[c + 6]), 0.f);
        float f7 = fmaxf(fmaf(__uint_as_float(u.w & 0xFFFF0000u), ssc[c + 7], ssh[c + 7]), 0.f);
        uint4 pk;
        pk.x = (unsigned)f2b(f0) | ((unsigned)f2b(f1) << 16);
        pk.y = (unsigned)f2b(f2) | ((unsigned)f2b(f3) << 16);
        pk.z = (unsigned)f2b(f4) | ((unsigned)f2b(f5) << 16);
        pk.w = (unsigned)f2b(f6) | ((unsigned)f2b(f7) << 16);
        int idx = row * 64 + (((g * 16) ^ ((row & 7) << 4)) >> 1);
        *(uint4*)&featA[idx] = pk;
    }
    __syncthreads();
    // K-loop: wave tile = 64 rows x OC cols
    const int w = tid >> 6, l = tid & 63;
    const int lr = l & 15, lg = l >> 4;
    const int wrow0 = w * 64;
    f32x4 acc[4][OC / 16];
#pragma unroll
    for (int mf = 0; mf < 4; ++mf)
#pragma unroll
        for (int nf = 0; nf < OC / 16; ++nf)
#pragma unroll
            for (int r = 0; r < 4; ++r) acc[mf][nf][r] = 0.0f;
#pragma unroll
    for (int kc = 0; kc < 2; ++kc) {
        const int kb = kc * 64 + lg * 16;   // byte offset of this lane's 8 k-elems
        bf16x8 bfr[OC / 16];
#pragma unroll
        for (int nf = 0; nf < OC / 16; ++nf) {
            int och = nf * 16 + lr;
            bfr[nf] = *(const bf16x8*)&wlT[och * 64 + ((kb ^ ((och & 7) << 4)) >> 1)];
        }
#pragma unroll
        for (int mf = 0; mf < 4; ++mf) {
            int row = wrow0 + mf * 16 + lr;
            bf16x8 af = *(const bf16x8*)&featA[row * 64 + ((kb ^ ((row & 7) << 4)) >> 1)];
#pragma unroll
            for (int nf = 0; nf < OC / 16; ++nf)
                acc[mf][nf] = __builtin_amdgcn_mfma_f32_16x16x32_bf16(
                    af, bfr[nf], acc[mf][nf], 0, 0, 0);
        }
    }
    // epilogue: bias, per-och stats; LAST: per-32-row-group max/min (pool fusion)
    const int gwave = blk * 4 + w;
#pragma unroll
    for (int nf = 0; nf < OC / 16; ++nf) {
        const int och = nf * 16 + lr;
        const float bv = bias[och];
        float s1 = 0.f, s2 = 0.f;
        float mx0 = -1e30f, mn0 = 1e30f, mx1 = -1e30f, mn1 = 1e30f;
#pragma unroll
        for (int mf = 0; mf < 4; ++mf) {
#pragma unroll
            for (int r = 0; r < 4; ++r) {
                float y = acc[mf][nf][r] + bv;
                s1 += y;
                s2 = fmaf(y, y, s2);
                if (LAST) {
                    if (mf < 2) { mx0 = fmaxf(mx0, y); mn0 = fminf(mn0, y); }
                    else        { mx1 = fmaxf(mx1, y); mn1 = fminf(mn1, y); }
                } else {
                    int gr = r0 + wrow0 + mf * 16 + lg * 4 + r;
                    yout[(size_t)gr * OC + och] = f2b(y);
                }
            }
        }
        s1 += __shfl_xor(s1, 16); s1 += __shfl_xor(s1, 32);
        s2 += __shfl_xor(s2, 16); s2 += __shfl_xor(s2, 32);
        if (LAST) {
            mx0 = fmaxf(mx0, __shfl_xor(mx0, 16)); mx0 = fmaxf(mx0, __shfl_xor(mx0, 32));
            mn0 = fminf(mn0, __shfl_xor(mn0, 16)); mn0 = fminf(mn0, __shfl_xor(mn0, 32));
            mx1 = fmaxf(mx1, __shfl_xor(mx1, 16)); mx1 = fmaxf(mx1, __shfl_xor(mx1, 32));
            mn1 = fminf(mn1, __shfl_xor(mn1, 16)); mn1 = fminf(mn1, __shfl_xor(mn1, 32));
        }
        if (l < 16) {
            ps[och * NW + gwave] = s1;
            pq[och * NW + gwave] = s2;
            if (LAST) {
                int grp0 = blk * 8 + w * 2;    // 32-row groups
                maxb[(size_t)grp0 * OC + och] = mx0;
                minb[(size_t)grp0 * OC + och] = mn0;
                maxb[(size_t)(grp0 + 1) * OC + och] = mx1;
                minb[(size_t)(grp0 + 1) * OC + och] = mn1;
            }
        }
    }
}

// ---------------- BN stats reduce -> scale/shift ----------------
template <int NPART>
__global__ __launch_bounds__(256) void bn_reduce_kernel(
    const float* __restrict__ ps, const float* __restrict__ pq,
    const float* __restrict__ gamma, const float* __restrict__ beta,
    float* __restrict__ scale, float* __restrict__ shift) {
    const int o = blockIdx.x, t = threadIdx.x;
    float s1 = 0.f, s2 = 0.f;
    for (int i = t; i < NPART; i += 256) {
        s1 += ps[o * NPART + i];
        s2 += pq[o * NPART + i];
    }
#pragma unroll
    for (int m = 32; m >= 1; m >>= 1) { s1 += __shfl_xor(s1, m); s2 += __shfl_xor(s2, m); }
    __shared__ float a1[4], a2[4];
    if ((t & 63) == 0) { a1[t >> 6] = s1; a2[t >> 6] = s2; }
    __syncthreads();
    if (t == 0) {
        float S1 = a1[0] + a1[1] + a1[2] + a1[3];
        float S2 = a2[0] + a2[1] + a2[2] + a2[3];
        const float inv = 1.0f / (float)M_TOT;
        float mean = S1 * inv;
        float var = S2 * inv - mean * mean;
        if (var < 0.f) var = 0.f;
        float rstd = 1.0f / sqrtf(var + 1e-5f);
        float sc = rstd * gamma[o];
        scale[o] = sc;
        shift[o] = beta[o] - mean * sc;
    }
}

// ---------------- pool2: BN3 applied to fused max/min extremes + relu ----------------
__global__ __launch_bounds__(256) void pool2_kernel(
    const float* __restrict__ maxb, const float* __restrict__ minb,
    const float* __restrict__ scale, const float* __restrict__ shift,
    float* __restrict__ outp) {
    int idx = blockIdx.x * 256 + threadIdx.x;   // = grp*128 + och
    int och = idx & 127;
    float sc = scale[och], sh = shift[och];
    float a = fmaf(maxb[idx], sc, sh);
    float b = fmaf(minb[idx], sc, sh);
    outp[idx] = fmaxf(fmaxf(a, b), 0.0f);   // bn linear -> max at an extreme; relu commutes
}

extern "C" void kernel_launch(void* const* d_in, const int* in_sizes, int n_in,
                              void* d_out, int out_size, void* d_ws, size_t ws_size,
                              hipStream_t stream) {
    const float* xyz    = (const float*)d_in[0];
    const float* points = (const float*)d_in[1];
    const float* w0  = (const float*)d_in[2];
    const float* b0  = (const float*)d_in[3];
    const float* g0  = (const float*)d_in[4];
    const float* be0 = (const float*)d_in[5];
    const float* w1  = (const float*)d_in[6];
    const float* b1  = (const float*)d_in[7];
    const float* g1  = (const float*)d_in[8];
    const float* be1 = (const float*)d_in[9];
    const float* w2  = (const float*)d_in[10];
    const float* b2  = (const float*)d_in[11];
    const float* g2  = (const float*)d_in[12];
    const float* be2 = (const float*)d_in[13];

    float* out = (float*)d_out;           // [0,24576) new_xyz, [24576,...) new_points
    char* ws = (char*)d_ws;
    int*   idxbuf = (int*)ws;                              // @0, 1 MB
    float* ps  = (float*)(ws + (1 << 20));                 // 2 MB (128ch x 4096 max)
    float* pq  = (float*)(ws + (3 << 20));                 // 2 MB
    float* st  = (float*)(ws + (5 << 20));                 // scale/shift x3 layers
    float *sc0 = st,        *sh0 = st + 128;
    float *sc1 = st + 256,  *sh1 = st + 384;
    float *sc2 = st + 512,  *sh2 = st + 640;
    float* maxb = (float*)(ws + (6 << 20));                // 4 MB (8192 grp x 128)
    float* minb = (float*)(ws + (10 << 20));               // 4 MB
    unsigned short* y1 = (unsigned short*)(ws + (14 << 20));  // 32 MB (bf16)
    unsigned short* y2 = (unsigned short*)(ws + (46 << 20));  // 32 MB
    // total ws footprint: 78 MB

    fps_kernel<<<8, 512, 0, stream>>>(xyz, out);
    qb_kernel<<<2048, 256, 0, stream>>>(xyz, out, idxbuf);
    layer1_kernel<<<NBLK, 256, 0, stream>>>(xyz, points, out, idxbuf, w0, b0, y1, ps, pq);
    bn_reduce_kernel<NBLK><<<64, 256, 0, stream>>>(ps, pq, g0, be0, sc0, sh0);
    layerM_kernel<64, false><<<M_TOT / 256, 256, 0, stream>>>(
        y1, sc0, sh0, w1, b1, y2, ps, pq, nullptr, nullptr);
    bn_reduce_kernel<NW><<<64, 256, 0, stream>>>(ps, pq, g1, be1, sc1, sh1);
    layerM_kernel<128, true><<<M_TOT / 256, 256, 0, stream>>>(
        y2, sc1, sh1, w2, b2, nullptr, ps, pq, maxb, minb);
    bn_reduce_kernel<NW><<<128, 256, 0, stream>>>(ps, pq, g2, be2, sc2, sh2);
    pool2_kernel<<<4096, 256, 0, stream>>>(maxb, minb, sc2, sh2, out + 24576);
}

// Round 6
// 848.973 us; speedup vs baseline: 1.1942x; 1.0051x over previous
//
#include <hip/hip_runtime.h>

#define DI __device__ __forceinline__

#define B_ 8
#define N_ 4096
#define S_ 1024
#define K_ 32
#define M_TOT (B_ * S_ * K_)   // 262144 rows
#define NBLK 2048              // L1 partial-stat blocks (128 rows each)
#define NW 4096                // L2/L3 per-wave partials (64 rows each)

typedef short bf16x8 __attribute__((ext_vector_type(8)));
typedef float f32x4 __attribute__((ext_vector_type(4)));

// Exact-IEEE squared distance, matching numpy f32 eval order ((dx*dx+dy*dy)+dz*dz),
// _rn intrinsics block FMA contraction so indices match the reference bit-exactly.
DI float sqdist_rn(float ax, float ay, float az, float bx, float by, float bz) {
    float dx = __fsub_rn(ax, bx);
    float dy = __fsub_rn(ay, by);
    float dz = __fsub_rn(az, bz);
    return __fadd_rn(__fadd_rn(__fmul_rn(dx, dx), __fmul_rn(dy, dy)), __fmul_rn(dz, dz));
}

DI unsigned short f2b(float f) {  // f32 -> bf16 RNE
    unsigned u = __float_as_uint(f);
    return (unsigned short)((u + 0x7FFFu + ((u >> 16) & 1u)) >> 16);
}
DI float b2f(unsigned short h) { return __uint_as_float(((unsigned)h) << 16); }

// DPP permutation applied to a u64 as two 32-bit halves (VALU-speed cross-lane).
template <int CTRL>
DI unsigned long long dpp_u64(unsigned long long v) {
    unsigned lo = (unsigned)__builtin_amdgcn_update_dpp(
        0, (int)(unsigned)v, CTRL, 0xF, 0xF, true);
    unsigned hi = (unsigned)__builtin_amdgcn_update_dpp(
        0, (int)(unsigned)(v >> 32), CTRL, 0xF, 0xF, true);
    return ((unsigned long long)hi << 32) | lo;
}
DI unsigned long long umax64(unsigned long long a, unsigned long long b) {
    return a > b ? a : b;
}

// ---------------- Mega-kernel LDS union: fps role / worker role ----------------
struct FpsSh { float4 pts[N_]; unsigned long long part[2][8]; };          // 65664 B
struct WrkSh { float feat[128 * 76]; float wl[64 * 76]; int idxl[128]; }; // 58880 B
union MegaSh { FpsSh f; WrkSh w; };

// ---------------- FPS role (R2-proven structure, 1 barrier/step, DPP reduce) ----------
// Publishes a per-batch ready-counter every 32 centers (release) for worker blocks.
DI void fps_role(const float* __restrict__ xyz, float* __restrict__ new_xyz,
                 unsigned* __restrict__ cnt, MegaSh& sh) {
    const int b = blockIdx.x;
    const int t = threadIdx.x;
    const float* X = xyz + (size_t)b * (N_ * 3);
    float px[8], py[8], pz[8], dd[8];
#pragma unroll
    for (int j = 0; j < 8; ++j) {
        int p = t + 512 * j;
        float x = X[p * 3 + 0], y = X[p * 3 + 1], z = X[p * 3 + 2];
        px[j] = x; py[j] = y; pz[j] = z; dd[j] = 1e10f;
        sh.f.pts[p] = make_float4(x, y, z, 0.0f);
    }
    if (t == 0) {
        new_xyz[(size_t)b * (S_ * 3) + 0] = px[0];
        new_xyz[(size_t)b * (S_ * 3) + 1] = py[0];
        new_xyz[(size_t)b * (S_ * 3) + 2] = pz[0];
    }
    __syncthreads();
    float4 cent = sh.f.pts[0];
    for (int i = 1; i < S_; ++i) {
        unsigned long long k0[8];
#pragma unroll
        for (int j = 0; j < 8; ++j) {
            float d = sqdist_rn(px[j], py[j], pz[j], cent.x, cent.y, cent.z);
            dd[j] = fminf(dd[j], d);
            k0[j] = ((unsigned long long)__float_as_uint(dd[j]) << 32) |
                    (unsigned long long)(~(unsigned)(t + 512 * j));
        }
        k0[0] = umax64(k0[0], k0[1]);
        k0[2] = umax64(k0[2], k0[3]);
        k0[4] = umax64(k0[4], k0[5]);
        k0[6] = umax64(k0[6], k0[7]);
        k0[0] = umax64(k0[0], k0[2]);
        k0[4] = umax64(k0[4], k0[6]);
        unsigned long long key = umax64(k0[0], k0[4]);
        key = umax64(key, dpp_u64<0x111>(key));  // row_shr:1
        key = umax64(key, dpp_u64<0x112>(key));  // row_shr:2
        key = umax64(key, dpp_u64<0x114>(key));  // row_shr:4
        key = umax64(key, dpp_u64<0x118>(key));  // row_shr:8
        key = umax64(key, dpp_u64<0x142>(key));  // row_bcast15
        key = umax64(key, dpp_u64<0x143>(key));  // row_bcast31
        if ((t & 63) == 63) sh.f.part[i & 1][t >> 6] = key;
        __syncthreads();
        ulonglong2 q0 = *(const ulonglong2*)&sh.f.part[i & 1][0];
        ulonglong2 q1 = *(const ulonglong2*)&sh.f.part[i & 1][2];
        ulonglong2 q2 = *(const ulonglong2*)&sh.f.part[i & 1][4];
        ulonglong2 q3 = *(const ulonglong2*)&sh.f.part[i & 1][6];
        unsigned long long ka = umax64(umax64(q0.x, q0.y), umax64(q1.x, q1.y));
        unsigned long long kb = umax64(umax64(q2.x, q2.y), umax64(q3.x, q3.y));
        unsigned long long k = umax64(ka, kb);
        unsigned gidx = ~(unsigned)(k & 0xFFFFFFFFull);
        cent = sh.f.pts[gidx];  // uniform address -> LDS broadcast
        if (t == 0) {
            size_t o3 = ((size_t)b * S_ + i) * 3;
            new_xyz[o3 + 0] = cent.x;
            new_xyz[o3 + 1] = cent.y;
            new_xyz[o3 + 2] = cent.z;
            if ((i & 31) == 31) {   // chunked publish: centers [0,i] ready
                __threadfence();
                __hip_atomic_store(&cnt[b], (unsigned)(i + 1),
                                   __ATOMIC_RELEASE, __HIP_MEMORY_SCOPE_AGENT);
            }
        }
    }
}

// ---------------- worker GEMM (512 thr): 128 rows x 64 outs, f32 register tile ---------
DI void gemm512(const float* __restrict__ feat, const float* __restrict__ wl,
                const float* __restrict__ bias, unsigned short* __restrict__ yout,
                float* __restrict__ ps, float* __restrict__ pq, int tile, int tid) {
    const int tr = tid & 15;
    const int tc = tid >> 4;            // 0..31
    const int r0 = tile * 128;
    float acc[8][2];
#pragma unroll
    for (int rr = 0; rr < 8; ++rr) { acc[rr][0] = 0.f; acc[rr][1] = 0.f; }
#pragma unroll 2
    for (int sl = 0; sl < 18; ++sl) {
        float4 xv[8], wv[2];
#pragma unroll
        for (int rr = 0; rr < 8; ++rr)
            xv[rr] = *(const float4*)&feat[(tr + 16 * rr) * 76 + 4 * sl];
#pragma unroll
        for (int cc = 0; cc < 2; ++cc)
            wv[cc] = *(const float4*)&wl[(tc + 32 * cc) * 76 + 4 * sl];
#pragma unroll
        for (int rr = 0; rr < 8; ++rr)
#pragma unroll
            for (int cc = 0; cc < 2; ++cc)
                acc[rr][cc] = fmaf(xv[rr].x, wv[cc].x,
                               fmaf(xv[rr].y, wv[cc].y,
                                fmaf(xv[rr].z, wv[cc].z,
                                 fmaf(xv[rr].w, wv[cc].w, acc[rr][cc]))));
    }
#pragma unroll
    for (int cc = 0; cc < 2; ++cc) {
        const int och = tc + 32 * cc;
        const float bv = bias[och];
        float s1 = 0.f, s2 = 0.f;
#pragma unroll
        for (int rr = 0; rr < 8; ++rr) {
            float y = acc[rr][cc] + bv;
            yout[(size_t)(r0 + tr + 16 * rr) * 64 + och] = f2b(y);
            s1 += y;
            s2 = fmaf(y, y, s2);
        }
#pragma unroll
        for (int m = 1; m < 16; m <<= 1) {
            s1 += __shfl_xor(s1, m);
            s2 += __shfl_xor(s2, m);
        }
        if ((tid & 15) == 0) {
            ps[och * NBLK + tile] = s1;
            pq[och * NBLK + tile] = s2;
        }
    }
}

// ---------------- worker role: wait for centers -> qb (4 waves) -> gather -> GEMM ------
DI void worker_role(const float* __restrict__ xyz, const float* __restrict__ points,
                    const float* __restrict__ new_xyz, const float* __restrict__ W0,
                    const float* __restrict__ bias0, unsigned short* __restrict__ yout,
                    float* __restrict__ ps, float* __restrict__ pq,
                    const unsigned* __restrict__ cnt, MegaSh& sh, int nWrk) {
    const int t = threadIdx.x;
    // s-major sweep: g -> (s-group q, batch b); workers stay in lockstep with production
    for (int g = (int)blockIdx.x - 8; g < 2048; g += nWrk) {
        const int q = g >> 3;
        const int b = g & 7;
        const int s0 = q * 4;
        const int tile = b * 256 + q;    // output row-block index
        if (t == 0) {
            while (__hip_atomic_load(&cnt[b], __ATOMIC_ACQUIRE,
                                     __HIP_MEMORY_SCOPE_AGENT) < (unsigned)(s0 + 4))
                __builtin_amdgcn_s_sleep(32);
        }
        __syncthreads();   // all threads wait for t0's acquire
        // ball query: wave w (0..3) handles center s0+w; first-32 compaction into LDS
        const int w = t >> 6, lane = t & 63;
        if (w < 4) {
            const int c = b * 1024 + s0 + w;
            const float* X = xyz + (size_t)b * (N_ * 3);
            const float cx = new_xyz[c * 3 + 0];
            const float cy = new_xyz[c * 3 + 1];
            const float cz = new_xyz[c * 3 + 2];
            int* out = &sh.w.idxl[w * K_];
            int taken = 0, first = -1;
            for (int ch = 0; ch < 64; ++ch) {
                int p = ch * 64 + lane;
                float d = sqdist_rn(X[p * 3 + 0], X[p * 3 + 1], X[p * 3 + 2], cx, cy, cz);
                bool ok = (d <= 0.25f);
                unsigned long long m = __ballot(ok);
                if (first < 0 && m) first = ch * 64 + (__ffsll((unsigned long long)m) - 1);
                int pos = taken + (int)__popcll(m & ((1ull << lane) - 1ull));
                if (ok && pos < K_) out[pos] = p;
                taken += (int)__popcll(m);
                if (taken >= K_) break;
            }
            int filled = taken < K_ ? taken : K_;
            if (lane >= filled && lane < K_) out[lane] = first;
        }
        __syncthreads();
        // stage weights (zero-padded ch 6,7) + gathered features
        for (int jj = t; jj < 64 * 70; jj += 512) {
            int o = jj / 70;
            int i2 = jj - o * 70;
            int mch = (i2 < 6) ? i2 : (i2 + 2);
            sh.w.wl[o * 76 + mch] = W0[jj];
        }
        if (t < 128) sh.w.wl[(t >> 1) * 76 + 6 + (t & 1)] = 0.0f;
        {
            const int row = t >> 2, h = t & 3;
            const int k = row & 31, cloc = row >> 5;
            const int pi = sh.w.idxl[cloc * 32 + k];
            const float* P = points + ((size_t)b * N_ + pi) * 64 + h * 16;
            float* fr = &sh.w.feat[row * 76];
#pragma unroll
            for (int qq = 0; qq < 4; ++qq)
                *(float4*)(fr + 8 + h * 16 + 4 * qq) = *(const float4*)(P + 4 * qq);
            if (h == 0) {
                size_t pb = ((size_t)b * N_ + pi) * 3;
                float x = xyz[pb + 0], y = xyz[pb + 1], z = xyz[pb + 2];
                const float* C = new_xyz + ((size_t)b * S_ + s0 + cloc) * 3;
                fr[0] = x; fr[1] = y; fr[2] = z;
                fr[3] = x - C[0]; fr[4] = y - C[1]; fr[5] = z - C[2];
                fr[6] = 0.0f; fr[7] = 0.0f;
            }
        }
        __syncthreads();
        gemm512(sh.w.feat, sh.w.wl, bias0, yout, ps, pq, tile, t);
        __syncthreads();   // LDS reused next tile
    }
}

__global__ __launch_bounds__(512) void mega_kernel(
    const float* __restrict__ xyz, const float* __restrict__ points,
    float* __restrict__ new_xyz, const float* __restrict__ w0,
    const float* __restrict__ b0, unsigned short* __restrict__ y1,
    float* __restrict__ ps, float* __restrict__ pq,
    unsigned* __restrict__ cnt, int nWrk) {
    __shared__ MegaSh sh;
    if (blockIdx.x < 8)
        fps_role(xyz, new_xyz, cnt, sh);
    else
        worker_role(xyz, points, new_xyz, w0, b0, y1, ps, pq, cnt, sh, nWrk);
}

// ---------------- Layers 2/3 (MFMA bf16): unchanged from R4 (passing) ----------------
template <int OC, bool LAST>
__global__ __launch_bounds__(256) void layerM_kernel(
    const unsigned short* __restrict__ yin,
    const float* __restrict__ scale, const float* __restrict__ shift,
    const float* __restrict__ W, const float* __restrict__ bias,
    unsigned short* __restrict__ yout,
    float* __restrict__ ps, float* __restrict__ pq,
    float* __restrict__ maxb, float* __restrict__ minb) {
    const int tid = threadIdx.x;
    const int blk = blockIdx.x;
    const int r0 = blk * 256;
    __shared__ unsigned short featA[256 * 64];   // 32 KB, swizzled
    __shared__ unsigned short wlT[OC * 64];      // swizzled
    __shared__ float ssc[64], ssh[64];
    if (tid < 64) { ssc[tid] = scale[tid]; ssh[tid] = shift[tid]; }
#pragma unroll
    for (int it = 0; it < OC / 16; ++it) {
        int q = it * 256 + tid;
        int och = q >> 4;
        int qq = q & 15;
        float4 wv = *(const float4*)&W[q * 4];
        uint2 pk;
        pk.x = (unsigned)f2b(wv.x) | ((unsigned)f2b(wv.y) << 16);
        pk.y = (unsigned)f2b(wv.z) | ((unsigned)f2b(wv.w) << 16);
        int idx = och * 64 + (((qq * 8) ^ ((och & 7) << 4)) >> 1);
        *(uint2*)&wlT[idx] = pk;
    }
    __syncthreads();
#pragma unroll
    for (int it = 0; it < 8; ++it) {
        int f = it * 256 + tid;
        int row = f >> 3, g = f & 7;
        uint4 u = *(const uint4*)&yin[(size_t)(r0 + row) * 64 + g * 8];
        int c = g * 8;
        float f0 = fmaxf(fmaf(__uint_as_float(u.x << 16),         ssc[c + 0], ssh[c + 0]), 0.f);
        float f1 = fmaxf(fmaf(__uint_as_float(u.x & 0xFFFF0000u), ssc[c + 1], ssh[c + 1]), 0.f);
        float f2 = fmaxf(fmaf(__uint_as_float(u.y << 16),         ssc[c + 2], ssh[c + 2]), 0.f);
        float f3 = fmaxf(fmaf(__uint_as_float(u.y & 0xFFFF0000u), ssc[c + 3], ssh[c + 3]), 0.f);
        float f4 = fmaxf(fmaf(__uint_as_float(u.z << 16),         ssc[c + 4], ssh[c + 4]), 0.f);
        float f5 = fmaxf(fmaf(__uint_as_float(u.z & 0xFFFF0000u), ssc[c + 5], ssh[c + 5]), 0.f);
        float f6 = fmaxf(fmaf(__uint_as_float(u.w << 16),         ssc[c + 6], ssh[c + 6]), 0.f);
        float f7 = fmaxf(fmaf(__uint_as_float(u.w & 0xFFFF0000u), ssc[c + 7], ssh[c + 7]), 0.f);
        uint4 pk;
        pk.x = (unsigned)f2b(f0) | ((unsigned)f2b(f1) << 16);
        pk.y = (unsigned)f2b(f2) | ((unsigned)f2b(f3) << 16);
        pk.z = (unsigned)f2b(f4) | ((unsigned)f2b(f5) << 16);
        pk.w = (unsigned)f2b(f6) | ((unsigned)f2b(f7) << 16);
        int idx = row * 64 + (((g * 16) ^ ((row & 7) << 4)) >> 1);
        *(uint4*)&featA[idx] = pk;
    }
    __syncthreads();
    const int w = tid >> 6, l = tid & 63;
    const int lr = l & 15, lg = l >> 4;
    const int wrow0 = w * 64;
    f32x4 acc[4][OC / 16];
#pragma unroll
    for (int mf = 0; mf < 4; ++mf)
#pragma unroll
        for (int nf = 0; nf < OC / 16; ++nf)
#pragma unroll
            for (int r = 0; r < 4; ++r) acc[mf][nf][r] = 0.0f;
#pragma unroll
    for (int kc = 0; kc < 2; ++kc) {
        const int kb = kc * 64 + lg * 16;
        bf16x8 bfr[OC / 16];
#pragma unroll
        for (int nf = 0; nf < OC / 16; ++nf) {
            int och = nf * 16 + lr;
            bfr[nf] = *(const bf16x8*)&wlT[och * 64 + ((kb ^ ((och & 7) << 4)) >> 1)];
        }
#pragma unroll
        for (int mf = 0; mf < 4; ++mf) {
            int row = wrow0 + mf * 16 + lr;
            bf16x8 af = *(const bf16x8*)&featA[row * 64 + ((kb ^ ((row & 7) << 4)) >> 1)];
#pragma unroll
            for (int nf = 0; nf < OC / 16; ++nf)
                acc[mf][nf] = __builtin_amdgcn_mfma_f32_16x16x32_bf16(
                    af, bfr[nf], acc[mf][nf], 0, 0, 0);
        }
    }
    const int gwave = blk * 4 + w;
#pragma unroll
    for (int nf = 0; nf < OC / 16; ++nf) {
        const int och = nf * 16 + lr;
        const float bv = bias[och];
        float s1 = 0.f, s2 = 0.f;
        float mx0 = -1e30f, mn0 = 1e30f, mx1 = -1e30f, mn1 = 1e30f;
#pragma unroll
        for (int mf = 0; mf < 4; ++mf) {
#pragma unroll
            for (int r = 0; r < 4; ++r) {
                float y = acc[mf][nf][r] + bv;
                s1 += y;
                s2 = fmaf(y, y, s2);
                if (LAST) {
                    if (mf < 2) { mx0 = fmaxf(mx0, y); mn0 = fminf(mn0, y); }
                    else        { mx1 = fmaxf(mx1, y); mn1 = fminf(mn1, y); }
                } else {
                    int gr = r0 + wrow0 + mf * 16 + lg * 4 + r;
                    yout[(size_t)gr * OC + och] = f2b(y);
                }
            }
        }
        s1 += __shfl_xor(s1, 16); s1 += __shfl_xor(s1, 32);
        s2 += __shfl_xor(s2, 16); s2 += __shfl_xor(s2, 32);
        if (LAST) {
            mx0 = fmaxf(mx0, __shfl_xor(mx0, 16)); mx0 = fmaxf(mx0, __shfl_xor(mx0, 32));
            mn0 = fminf(mn0, __shfl_xor(mn0, 16)); mn0 = fminf(mn0, __shfl_xor(mn0, 32));
            mx1 = fmaxf(mx1, __shfl_xor(mx1, 16)); mx1 = fmaxf(mx1, __shfl_xor(mx1, 32));
            mn1 = fminf(mn1, __shfl_xor(mn1, 16)); mn1 = fminf(mn1, __shfl_xor(mn1, 32));
        }
        if (l < 16) {
            ps[och * NW + gwave] = s1;
            pq[och * NW + gwave] = s2;
            if (LAST) {
                int grp0 = blk * 8 + w * 2;
                maxb[(size_t)grp0 * OC + och] = mx0;
                minb[(size_t)grp0 * OC + och] = mn0;
                maxb[(size_t)(grp0 + 1) * OC + och] = mx1;
                minb[(size_t)(grp0 + 1) * OC + och] = mn1;
            }
        }
    }
}

// ---------------- BN stats reduce -> scale/shift ----------------
template <int NPART>
__global__ __launch_bounds__(256) void bn_reduce_kernel(
    const float* __restrict__ ps, const float* __restrict__ pq,
    const float* __restrict__ gamma, const float* __restrict__ beta,
    float* __restrict__ scale, float* __restrict__ shift) {
    const int o = blockIdx.x, t = threadIdx.x;
    float s1 = 0.f, s2 = 0.f;
    for (int i = t; i < NPART; i += 256) {
        s1 += ps[o * NPART + i];
        s2 += pq[o * NPART + i];
    }
#pragma unroll
    for (int m = 32; m >= 1; m >>= 1) { s1 += __shfl_xor(s1, m); s2 += __shfl_xor(s2, m); }
    __shared__ float a1[4], a2[4];
    if ((t & 63) == 0) { a1[t >> 6] = s1; a2[t >> 6] = s2; }
    __syncthreads();
    if (t == 0) {
        float S1 = a1[0] + a1[1] + a1[2] + a1[3];
        float S2 = a2[0] + a2[1] + a2[2] + a2[3];
        const float inv = 1.0f / (float)M_TOT;
        float mean = S1 * inv;
        float var = S2 * inv - mean * mean;
        if (var < 0.f) var = 0.f;
        float rstd = 1.0f / sqrtf(var + 1e-5f);
        float sc = rstd * gamma[o];
        scale[o] = sc;
        shift[o] = beta[o] - mean * sc;
    }
}

// ---------------- pool2: BN3 applied to fused max/min extremes + relu ----------------
__global__ __launch_bounds__(256) void pool2_kernel(
    const float* __restrict__ maxb, const float* __restrict__ minb,
    const float* __restrict__ scale, const float* __restrict__ shift,
    float* __restrict__ outp) {
    int idx = blockIdx.x * 256 + threadIdx.x;   // = grp*128 + och
    int och = idx & 127;
    float sc = scale[och], sh = shift[och];
    float a = fmaf(maxb[idx], sc, sh);
    float b = fmaf(minb[idx], sc, sh);
    outp[idx] = fmaxf(fmaxf(a, b), 0.0f);
}

extern "C" void kernel_launch(void* const* d_in, const int* in_sizes, int n_in,
                              void* d_out, int out_size, void* d_ws, size_t ws_size,
                              hipStream_t stream) {
    const float* xyz    = (const float*)d_in[0];
    const float* points = (const float*)d_in[1];
    const float* w0  = (const float*)d_in[2];
    const float* b0  = (const float*)d_in[3];
    const float* g0  = (const float*)d_in[4];
    const float* be0 = (const float*)d_in[5];
    const float* w1  = (const float*)d_in[6];
    const float* b1  = (const float*)d_in[7];
    const float* g1  = (const float*)d_in[8];
    const float* be1 = (const float*)d_in[9];
    const float* w2  = (const float*)d_in[10];
    const float* b2  = (const float*)d_in[11];
    const float* g2  = (const float*)d_in[12];
    const float* be2 = (const float*)d_in[13];

    float* out = (float*)d_out;           // [0,24576) new_xyz, [24576,...) new_points
    char* ws = (char*)d_ws;
    unsigned* cnt = (unsigned*)ws;                         // 8 ready-counters
    float* ps  = (float*)(ws + (1 << 20));                 // 2 MB (128ch x 4096 max)
    float* pq  = (float*)(ws + (3 << 20));                 // 2 MB
    float* st  = (float*)(ws + (5 << 20));                 // scale/shift x3 layers
    float *sc0 = st,        *sh0 = st + 128;
    float *sc1 = st + 256,  *sh1 = st + 384;
    float *sc2 = st + 512,  *sh2 = st + 640;
    float* maxb = (float*)(ws + (6 << 20));                // 4 MB (8192 grp x 128)
    float* minb = (float*)(ws + (10 << 20));               // 4 MB
    unsigned short* y1 = (unsigned short*)(ws + (14 << 20));  // 32 MB (bf16)
    unsigned short* y2 = (unsigned short*)(ws + (46 << 20));  // 32 MB

    // worker count from occupancy (co-residency required); deterministic per call
    int blocksPerCU = 0;
    hipOccupancyMaxActiveBlocksPerMultiprocessor(&blocksPerCU, mega_kernel, 512, 0);
    if (blocksPerCU < 1) blocksPerCU = 1;
    int grid = blocksPerCU * 256;
    if (grid > 2056) grid = 2056;
    int nWrk = grid - 8;

    hipMemsetAsync(cnt, 0, 8 * sizeof(unsigned), stream);

    void* args[] = {(void*)&xyz, (void*)&points, (void*)&out, (void*)&w0, (void*)&b0,
                    (void*)&y1, (void*)&ps, (void*)&pq, (void*)&cnt, (void*)&nWrk};
    hipLaunchCooperativeKernel(mega_kernel, dim3(grid), dim3(512), args, 0, stream);

    bn_reduce_kernel<NBLK><<<64, 256, 0, stream>>>(ps, pq, g0, be0, sc0, sh0);
    layerM_kernel<64, false><<<M_TOT / 256, 256, 0, stream>>>(
        y1, sc0, sh0, w1, b1, y2, ps, pq, nullptr, nullptr);
    bn_reduce_kernel<NW><<<64, 256, 0, stream>>>(ps, pq, g1, be1, sc1, sh1);
    layerM_kernel<128, true><<<M_TOT / 256, 256, 0, stream>>>(
        y2, sc1, sh1, w2, b2, nullptr, ps, pq, maxb, minb);
    bn_reduce_kernel<NW><<<128, 256, 0, stream>>>(ps, pq, g2, be2, sc2, sh2);
    pool2_kernel<<<4096, 256, 0, stream>>>(maxb, minb, sc2, sh2, out + 24576);
}